// Round 11
// baseline (186.007 us; speedup 1.0000x reference)
//
#include <hip/hip_runtime.h>
#include <cstddef>

typedef unsigned short u16;
typedef u16 u16x8 __attribute__((ext_vector_type(8)));
typedef __bf16 bf16x8 __attribute__((ext_vector_type(8)));  // matches V8y builtin sig
typedef float f32x4 __attribute__((ext_vector_type(4)));

static constexpr int V  = 2048;
static constexpr int DD = 64;   // D_IN == D_OUT

__device__ __forceinline__ u16 f2b(float f) {
  union { float f; unsigned int i; } x; x.f = f;
  return (u16)((x.i + 0x7fffu + ((x.i >> 16) & 1u)) >> 16);  // RNE
}

// ---- K1: partial column sums of adj (fp32): partial[b][c] = sum of 32 rows ----
__global__ __launch_bounds__(256) void k_part(const float* __restrict__ adj,
                                              float* __restrict__ partial) {
  int t = threadIdx.x;
  int r0 = blockIdx.x * 32;
  int c0 = t * 8;
  float acc[8] = {0.f, 0.f, 0.f, 0.f, 0.f, 0.f, 0.f, 0.f};
  for (int r = 0; r < 32; ++r) {
    const float* p = adj + (size_t)(r0 + r) * V + c0;
    #pragma unroll
    for (int k = 0; k < 8; ++k) acc[k] += p[k];
  }
  #pragma unroll
  for (int k = 0; k < 8; ++k) partial[(size_t)blockIdx.x * V + c0 + k] = acc[k];
}

// ---- K1b: rinv[c] = rsqrt(sum_b partial[b][c]) ----
__global__ __launch_bounds__(256) void k_rinv(const float* __restrict__ partial,
                                              float* __restrict__ rinv) {
  int c = blockIdx.x * 256 + threadIdx.x;
  float s = 0.f;
  for (int i = 0; i < 64; ++i) s += partial[(size_t)i * V + c];
  rinv[c] = rsqrtf(s);
}

// ---- KT: At[j][v] = adj[v][j] * rinv[v] * rinv[j]  (fp32 in, bf16 out) ----
__global__ __launch_bounds__(256) void k_tn(const float* __restrict__ adj,
                                            const float* __restrict__ rinv,
                                            u16* __restrict__ At) {
  __shared__ float T[64][65];
  int t = threadIdx.x;
  int v0 = blockIdx.x * 64;
  int j0 = blockIdx.y * 64;
  #pragma unroll
  for (int it = 0; it < 2; ++it) {
    int f = t + it * 256;
    int row = f >> 3;          // v offset
    int cc = (f & 7) * 8;      // j chunk
    float rv = rinv[v0 + row];
    const float* p = adj + (size_t)(v0 + row) * V + j0 + cc;
    #pragma unroll
    for (int k = 0; k < 8; ++k) T[row][cc + k] = p[k] * rv;
  }
  __syncthreads();
  #pragma unroll
  for (int it = 0; it < 2; ++it) {
    int f = t + it * 256;
    int jr = f >> 3;           // j offset
    int vc = (f & 7) * 8;      // v chunk
    float rj = rinv[j0 + jr];
    u16x8 o;
    #pragma unroll
    for (int k = 0; k < 8; ++k) o[k] = f2b(T[vc + k][jr] * rj);
    *(u16x8*)(At + (size_t)(j0 + jr) * V + v0 + vc) = o;
  }
}

// ---- K2: Yt[(ab*64+e)][v] = dot(x[ab,v,:], W[:,e])  (fp32 in, bf16 out) ----
__global__ __launch_bounds__(256) void k_proj(const float* __restrict__ x,
                                              const float* __restrict__ w,
                                              u16* __restrict__ Yt) {
  __shared__ float XL[64][65];   // x tile [v][d]; reused as [e][v] for output
  __shared__ float WL[64][64];   // W [d][e]
  int t = threadIdx.x;
  int ab = blockIdx.x >> 5;
  int v0 = (blockIdx.x & 31) * 64;
  const float* xb = x + ((size_t)ab * V + v0) * DD;  // contiguous 64x64 tile
  #pragma unroll
  for (int it = 0; it < 2; ++it) {
    int f = t + it * 256;
    int row = f >> 3;
    int cc = (f & 7) * 8;
    const float* px = xb + f * 8;
    const float* pw = w + f * 8;
    #pragma unroll
    for (int k = 0; k < 8; ++k) { XL[row][cc + k] = px[k]; WL[row][cc + k] = pw[k]; }
  }
  __syncthreads();
  int v = t & 63;
  int g = t >> 6;             // e-group: e in [g*16, g*16+16)
  float acc[16];
  #pragma unroll
  for (int e = 0; e < 16; ++e) acc[e] = 0.f;
  for (int d = 0; d < 64; ++d) {
    float xv = XL[v][d];
    #pragma unroll
    for (int e = 0; e < 16; ++e) acc[e] += xv * WL[d][g * 16 + e];
  }
  __syncthreads();
  #pragma unroll
  for (int e = 0; e < 16; ++e) XL[g * 16 + e][v] = acc[e];  // transpose via LDS
  __syncthreads();
  #pragma unroll
  for (int it = 0; it < 2; ++it) {
    int f = t + it * 256;
    int er = f >> 3;            // e row
    int vc = (f & 7) * 8;       // v chunk
    u16x8 o;
    #pragma unroll
    for (int k = 0; k < 8; ++k) o[k] = f2b(XL[er][vc + k]);
    *(u16x8*)(Yt + (size_t)(ab * 64 + er) * V + v0 + vc) = o;
  }
}

// ---- K3: OUT[j,n] = sum_v At[j,v]*Yt[n,v]; +bias, relu; FP32 out ----
#define BM 128
#define BN 128
#define BK 32
#define AST 40   // LDS row stride in u16: 80 B (16B-aligned chunks, 2-way-max banks)

__global__ __launch_bounds__(256) void k_gemm(const u16* __restrict__ At,
                                              const u16* __restrict__ Yt,
                                              const float* __restrict__ bias,
                                              float* __restrict__ out) {
  __shared__ u16 Al[BM * AST];
  __shared__ u16 Bl[BN * AST];
  int t = threadIdx.x;
  int m0 = blockIdx.x * BM;
  int n0 = blockIdx.y * BN;
  int lane = t & 63;
  int wave = t >> 6;
  int wm = (wave & 1) * 64;
  int wn = (wave >> 1) * 64;
  int q = lane >> 4;
  int r = lane & 15;

  const f32x4 vzero = {0.f, 0.f, 0.f, 0.f};
  f32x4 acc[4][4];
  #pragma unroll
  for (int i = 0; i < 4; ++i)
    #pragma unroll
    for (int j = 0; j < 4; ++j) acc[i][j] = vzero;

  int sr = t >> 2;          // staging row within 64-row pass
  int sc = (t & 3) * 8;     // staging k-chunk (8 bf16 = 16 B)

  for (int k0 = 0; k0 < V; k0 += BK) {
    // global -> regs (issued before barrier, overlaps prior LDS compute)
    u16x8 va[2], vb[2];
    #pragma unroll
    for (int p = 0; p < 2; ++p) {
      int row = p * 64 + sr;
      va[p] = *(const u16x8*)(At + (size_t)(m0 + row) * V + k0 + sc);
      vb[p] = *(const u16x8*)(Yt + (size_t)(n0 + row) * V + k0 + sc);
    }
    __syncthreads();   // previous iteration's LDS reads complete
    #pragma unroll
    for (int p = 0; p < 2; ++p) {
      int row = p * 64 + sr;
      *(u16x8*)(Al + row * AST + sc) = va[p];
      *(u16x8*)(Bl + row * AST + sc) = vb[p];
    }
    __syncthreads();
    bf16x8 a[4], b[4];
    #pragma unroll
    for (int i = 0; i < 4; ++i)
      a[i] = __builtin_bit_cast(bf16x8, *(const u16x8*)(Al + (wm + i * 16 + r) * AST + q * 8));
    #pragma unroll
    for (int j = 0; j < 4; ++j)
      b[j] = __builtin_bit_cast(bf16x8, *(const u16x8*)(Bl + (wn + j * 16 + r) * AST + q * 8));
    #pragma unroll
    for (int i = 0; i < 4; ++i)
      #pragma unroll
      for (int j = 0; j < 4; ++j)
        acc[i][j] = __builtin_amdgcn_mfma_f32_16x16x32_bf16(a[i], b[j], acc[i][j], 0, 0, 0);
  }

  // epilogue: D layout col(n) = lane&15, row(m) = (lane>>4)*4 + reg  -> fp32 store
  #pragma unroll
  for (int j = 0; j < 4; ++j) {
    int n = n0 + wn + j * 16 + r;
    int e = n & 63;
    int ab = n >> 6;
    float bv = bias[e];
    float* ob = out + (size_t)ab * (V * DD);
    #pragma unroll
    for (int i = 0; i < 4; ++i) {
      #pragma unroll
      for (int reg = 0; reg < 4; ++reg) {
        int jj = m0 + wm + i * 16 + q * 4 + reg;
        float val = acc[i][j][reg] + bv;
        float res = fmaxf(val, 0.f);
        // NaN sentinel: relu(NaN)=0 would silently hide poisoned accumulators.
        if (val != val) res = 999.0f;
        ob[(size_t)jj * DD + e] = res;
      }
    }
  }
}

extern "C" void kernel_launch(void* const* d_in, const int* in_sizes, int n_in,
                              void* d_out, int out_size, void* d_ws, size_t ws_size,
                              hipStream_t stream) {
  const float* adj  = (const float*)d_in[0];
  const float* x    = (const float*)d_in[1];
  const float* w    = (const float*)d_in[2];
  const float* bias = (const float*)d_in[3];
  float* out = (float*)d_out;

  char* ws = (char*)d_ws;
  float* partial = (float*)ws;                       // 64*2048 f32 = 512 KB
  float* rinv    = (float*)(ws + (size_t)(64 * V) * sizeof(float)); // 8 KB
  u16*   At      = (u16*)(ws + (1u << 20));          // 2048x2048 bf16 = 8 MB
  u16*   Yt      = (u16*)(ws + (9u << 20));          // 4096x2048 bf16 = 16 MB
  // total ws needed: 25 MB

  size_t out_bytes = (size_t)out_size * sizeof(float);  // fp32 output buffer

  // Canary: if k_gemm never stores, readback = fp32 ~48.56 everywhere.
  (void)hipMemsetAsync(out, 0x42, out_bytes, stream);
  (void)hipGetLastError();   // clear stale error

  k_part<<<64, 256, 0, stream>>>(adj, partial);
  if (hipGetLastError() != hipSuccess) { (void)hipMemsetAsync(out, 0x44, out_bytes, stream); return; }
  k_rinv<<<8, 256, 0, stream>>>(partial, rinv);
  if (hipGetLastError() != hipSuccess) { (void)hipMemsetAsync(out, 0x45, out_bytes, stream); return; }
  k_tn<<<dim3(32, 32), 256, 0, stream>>>(adj, rinv, At);
  if (hipGetLastError() != hipSuccess) { (void)hipMemsetAsync(out, 0x46, out_bytes, stream); return; }
  k_proj<<<2048, 256, 0, stream>>>(x, w, Yt);
  if (hipGetLastError() != hipSuccess) { (void)hipMemsetAsync(out, 0x47, out_bytes, stream); return; }
  k_gemm<<<dim3(16, 32), 256, 0, stream>>>(At, Yt, bias, out);
  if (hipGetLastError() != hipSuccess) { (void)hipMemsetAsync(out, 0x48, out_bytes, stream); return; }
}

// Round 12
// 172.994 us; speedup vs baseline: 1.0752x; 1.0752x over previous
//
#include <hip/hip_runtime.h>
#include <cstddef>

typedef unsigned short u16;
typedef u16 u16x8 __attribute__((ext_vector_type(8)));
typedef __bf16 bf16x8 __attribute__((ext_vector_type(8)));
typedef float f32x4 __attribute__((ext_vector_type(4)));

static constexpr int V  = 2048;
static constexpr int DD = 64;   // D_IN == D_OUT

__device__ __forceinline__ u16 f2b(float f) {
  union { float f; unsigned int i; } x; x.f = f;
  return (u16)((x.i + 0x7fffu + ((x.i >> 16) & 1u)) >> 16);  // RNE
}

__device__ __forceinline__ void gll16(const void* g, void* l) {
  __builtin_amdgcn_global_load_lds(
      (const __attribute__((address_space(1))) void*)g,
      (__attribute__((address_space(3))) void*)l, 16, 0, 0);
}

// ---- K1: partial column sums of adj: partial[b][c] = sum of 16 rows ----
__global__ __launch_bounds__(256) void k_part(const float* __restrict__ adj,
                                              float* __restrict__ partial) {
  int t = threadIdx.x;
  int r0 = blockIdx.x * 16;
  int c0 = t * 8;
  float acc[8] = {0.f, 0.f, 0.f, 0.f, 0.f, 0.f, 0.f, 0.f};
  for (int r = 0; r < 16; ++r) {
    const float4* p = (const float4*)(adj + (size_t)(r0 + r) * V + c0);
    float4 a0 = p[0], a1 = p[1];
    acc[0] += a0.x; acc[1] += a0.y; acc[2] += a0.z; acc[3] += a0.w;
    acc[4] += a1.x; acc[5] += a1.y; acc[6] += a1.z; acc[7] += a1.w;
  }
  #pragma unroll
  for (int k = 0; k < 8; ++k) partial[(size_t)blockIdx.x * V + c0 + k] = acc[k];
}

// ---- K1b: rinv[c] = rsqrt(sum_b partial[b][c]) ----
__global__ __launch_bounds__(256) void k_rinv(const float* __restrict__ partial,
                                              float* __restrict__ rinv) {
  int c = blockIdx.x * 256 + threadIdx.x;
  float s = 0.f;
  for (int i = 0; i < 128; ++i) s += partial[(size_t)i * V + c];
  rinv[c] = rsqrtf(s);
}

// ---- KT: At[j][v] = adj[v][j] * rinv[v] * rinv[j]  (fp32 in, bf16 out) ----
__global__ __launch_bounds__(256) void k_tn(const float* __restrict__ adj,
                                            const float* __restrict__ rinv,
                                            u16* __restrict__ At) {
  __shared__ float T[64][65];
  int t = threadIdx.x;
  int v0 = blockIdx.x * 64;
  int j0 = blockIdx.y * 64;
  #pragma unroll
  for (int it = 0; it < 2; ++it) {
    int f = t + it * 256;
    int row = f >> 3;          // v offset
    int cc = (f & 7) * 8;      // j chunk
    float rv = rinv[v0 + row];
    const float4* p = (const float4*)(adj + (size_t)(v0 + row) * V + j0 + cc);
    float4 a0 = p[0], a1 = p[1];
    T[row][cc + 0] = a0.x * rv; T[row][cc + 1] = a0.y * rv;
    T[row][cc + 2] = a0.z * rv; T[row][cc + 3] = a0.w * rv;
    T[row][cc + 4] = a1.x * rv; T[row][cc + 5] = a1.y * rv;
    T[row][cc + 6] = a1.z * rv; T[row][cc + 7] = a1.w * rv;
  }
  __syncthreads();
  #pragma unroll
  for (int it = 0; it < 2; ++it) {
    int f = t + it * 256;
    int jr = f >> 3;           // j offset
    int vc = (f & 7) * 8;      // v chunk
    float rj = rinv[j0 + jr];
    u16x8 o;
    #pragma unroll
    for (int k = 0; k < 8; ++k) o[k] = f2b(T[vc + k][jr] * rj);
    *(u16x8*)(At + (size_t)(j0 + jr) * V + v0 + vc) = o;
  }
}

// ---- K2: Yt[(ab*64+e)][v] = dot(x[ab,v,:], W[:,e])  (fp32 in, bf16 out) ----
__global__ __launch_bounds__(256) void k_proj(const float* __restrict__ x,
                                              const float* __restrict__ w,
                                              u16* __restrict__ Yt) {
  __shared__ float XL[64][65];   // x tile [v][d]; reused as [e][v] for output
  __shared__ float WL[64][64];   // W [d][e]
  int t = threadIdx.x;
  int ab = blockIdx.x >> 5;
  int v0 = (blockIdx.x & 31) * 64;
  const float* xb = x + ((size_t)ab * V + v0) * DD;  // contiguous 64x64 tile
  #pragma unroll
  for (int it = 0; it < 2; ++it) {
    int f = t + it * 256;
    int row = f >> 3;
    int cc = (f & 7) * 8;
    const float4* px = (const float4*)(xb + f * 8);
    const float4* pw = (const float4*)(w + f * 8);
    float4 x0 = px[0], x1 = px[1];
    float4 w0 = pw[0], w1 = pw[1];
    XL[row][cc + 0] = x0.x; XL[row][cc + 1] = x0.y;
    XL[row][cc + 2] = x0.z; XL[row][cc + 3] = x0.w;
    XL[row][cc + 4] = x1.x; XL[row][cc + 5] = x1.y;
    XL[row][cc + 6] = x1.z; XL[row][cc + 7] = x1.w;
    WL[row][cc + 0] = w0.x; WL[row][cc + 1] = w0.y;
    WL[row][cc + 2] = w0.z; WL[row][cc + 3] = w0.w;
    WL[row][cc + 4] = w1.x; WL[row][cc + 5] = w1.y;
    WL[row][cc + 6] = w1.z; WL[row][cc + 7] = w1.w;
  }
  __syncthreads();
  int v = t & 63;
  int g = t >> 6;             // e-group: e in [g*16, g*16+16)
  float acc[16];
  #pragma unroll
  for (int e = 0; e < 16; ++e) acc[e] = 0.f;
  for (int d = 0; d < 64; ++d) {
    float xv = XL[v][d];
    #pragma unroll
    for (int e = 0; e < 16; ++e) acc[e] += xv * WL[d][g * 16 + e];
  }
  __syncthreads();
  #pragma unroll
  for (int e = 0; e < 16; ++e) XL[g * 16 + e][v] = acc[e];  // transpose via LDS
  __syncthreads();
  #pragma unroll
  for (int it = 0; it < 2; ++it) {
    int f = t + it * 256;
    int er = f >> 3;            // e row
    int vc = (f & 7) * 8;       // v chunk
    u16x8 o;
    #pragma unroll
    for (int k = 0; k < 8; ++k) o[k] = f2b(XL[er][vc + k]);
    *(u16x8*)(Yt + (size_t)(ab * 64 + er) * V + v0 + vc) = o;
  }
}

// ---- K3: OUT[j,n] = sum_v At[j,v]*Yt[n,v]; +bias, relu; FP32 out ----
// m97-style: global_load_lds width-16 staging into unpadded BK=32 LDS tiles.
#define BM 128
#define BN 128
#define BK 32

__global__ __launch_bounds__(256) void k_gemm(const u16* __restrict__ At,
                                              const u16* __restrict__ Yt,
                                              const float* __restrict__ bias,
                                              float* __restrict__ out) {
  __shared__ u16 Al[BM * BK];   // 8 KB, row-major [m][k], unpadded
  __shared__ u16 Bl[BN * BK];   // 8 KB, [n][k]
  int t = threadIdx.x;
  int m0 = blockIdx.x * BM;
  int n0 = blockIdx.y * BN;
  int lane = t & 63;
  int wave = t >> 6;
  int wm = (wave & 1) * 64;
  int wn = (wave >> 1) * 64;
  int q = lane >> 4;
  int r = lane & 15;

  const f32x4 vzero = {0.f, 0.f, 0.f, 0.f};
  f32x4 acc[4][4];
  #pragma unroll
  for (int i = 0; i < 4; ++i)
    #pragma unroll
    for (int j = 0; j < 4; ++j) acc[i][j] = vzero;

  // Staging map: pass p, thread t handles u16 elements eo..eo+7 (16 B),
  // eo = (p*256+t)*8 -> row = eo>>5, col = eo&31. LDS byte addr is
  // wave-uniform base + lane*16 (global_load_lds requirement).
  int eo0 = t * 8;
  int eo1 = (256 + t) * 8;
  int row0 = eo0 >> 5, col0 = eo0 & 31;
  int row1 = eo1 >> 5, col1 = eo1 & 31;

  for (int k0 = 0; k0 < V; k0 += BK) {
    __syncthreads();   // previous iteration's frag reads complete
    gll16(At + (size_t)(m0 + row0) * V + k0 + col0, Al + eo0);
    gll16(At + (size_t)(m0 + row1) * V + k0 + col1, Al + eo1);
    gll16(Yt + (size_t)(n0 + row0) * V + k0 + col0, Bl + eo0);
    gll16(Yt + (size_t)(n0 + row1) * V + k0 + col1, Bl + eo1);
    __syncthreads();   // vmcnt drain + barrier (compiler inserts waitcnt)
    bf16x8 a[4], b[4];
    #pragma unroll
    for (int i = 0; i < 4; ++i)
      a[i] = __builtin_bit_cast(bf16x8, *(const u16x8*)(Al + (wm + i * 16 + r) * BK + q * 8));
    #pragma unroll
    for (int j = 0; j < 4; ++j)
      b[j] = __builtin_bit_cast(bf16x8, *(const u16x8*)(Bl + (wn + j * 16 + r) * BK + q * 8));
    #pragma unroll
    for (int i = 0; i < 4; ++i)
      #pragma unroll
      for (int j = 0; j < 4; ++j)
        acc[i][j] = __builtin_amdgcn_mfma_f32_16x16x32_bf16(a[i], b[j], acc[i][j], 0, 0, 0);
  }

  // epilogue: D layout col(n) = lane&15, row(m) = (lane>>4)*4 + reg
  #pragma unroll
  for (int j = 0; j < 4; ++j) {
    int n = n0 + wn + j * 16 + r;
    int e = n & 63;
    int ab = n >> 6;
    float bv = bias[e];
    float* ob = out + (size_t)ab * (V * DD);
    #pragma unroll
    for (int i = 0; i < 4; ++i) {
      #pragma unroll
      for (int reg = 0; reg < 4; ++reg) {
        int jj = m0 + wm + i * 16 + q * 4 + reg;
        ob[(size_t)jj * DD + e] = fmaxf(acc[i][j][reg] + bv, 0.f);
      }
    }
  }
}

extern "C" void kernel_launch(void* const* d_in, const int* in_sizes, int n_in,
                              void* d_out, int out_size, void* d_ws, size_t ws_size,
                              hipStream_t stream) {
  const float* adj  = (const float*)d_in[0];
  const float* x    = (const float*)d_in[1];
  const float* w    = (const float*)d_in[2];
  const float* bias = (const float*)d_in[3];
  float* out = (float*)d_out;

  // Workspace (24 MB, proven):
  //   At      @ 0    : 2048*2048 bf16 = 8 MB   (live k_tn..k_gemm)
  //   Yt      @ 8 MB : 4096*2048 bf16 = 16 MB  (live k_proj..k_gemm)
  //   partial @ 8 MB : 128*2048 f32 = 1 MB     (overlaps Yt; dead before k_proj)
  //   rinv    @ 9 MB : 2048 f32 = 8 KB         (read by k_tn, dead before k_proj)
  char* ws = (char*)d_ws;
  u16*   At      = (u16*)ws;
  u16*   Yt      = (u16*)(ws + ((size_t)8 << 20));
  float* partial = (float*)(ws + ((size_t)8 << 20));
  float* rinv    = (float*)(ws + ((size_t)9 << 20));

  k_part<<<128, 256, 0, stream>>>(adj, partial);
  k_rinv<<<8, 256, 0, stream>>>(partial, rinv);
  k_tn<<<dim3(32, 32), 256, 0, stream>>>(adj, rinv, At);
  k_proj<<<2048, 256, 0, stream>>>(x, w, Yt);
  k_gemm<<<dim3(16, 32), 256, 0, stream>>>(At, Yt, bias, out);
}

// Round 13
// 153.744 us; speedup vs baseline: 1.2098x; 1.1252x over previous
//
#include <hip/hip_runtime.h>
#include <cstddef>

typedef unsigned short u16;
typedef u16 u16x8 __attribute__((ext_vector_type(8)));
typedef __bf16 bf16x8 __attribute__((ext_vector_type(8)));
typedef float f32x4 __attribute__((ext_vector_type(4)));

static constexpr int V  = 2048;
static constexpr int DD = 64;   // D_IN == D_OUT

__device__ __forceinline__ u16 f2b(float f) {
  union { float f; unsigned int i; } x; x.f = f;
  return (u16)((x.i + 0x7fffu + ((x.i >> 16) & 1u)) >> 16);  // RNE
}

__device__ __forceinline__ void gll16(const void* g, void* l) {
  __builtin_amdgcn_global_load_lds(
      (const __attribute__((address_space(1))) void*)g,
      (__attribute__((address_space(3))) void*)l, 16, 0, 0);
}

// ---- K1: partial column sums of adj: partial[b][c] = sum of 16 rows ----
__global__ __launch_bounds__(256) void k_part(const float* __restrict__ adj,
                                              float* __restrict__ partial) {
  int t = threadIdx.x;
  int r0 = blockIdx.x * 16;
  int c0 = t * 8;
  float acc[8] = {0.f, 0.f, 0.f, 0.f, 0.f, 0.f, 0.f, 0.f};
  for (int r = 0; r < 16; ++r) {
    const float4* p = (const float4*)(adj + (size_t)(r0 + r) * V + c0);
    float4 a0 = p[0], a1 = p[1];
    acc[0] += a0.x; acc[1] += a0.y; acc[2] += a0.z; acc[3] += a0.w;
    acc[4] += a1.x; acc[5] += a1.y; acc[6] += a1.z; acc[7] += a1.w;
  }
  #pragma unroll
  for (int k = 0; k < 8; ++k) partial[(size_t)blockIdx.x * V + c0 + k] = acc[k];
}

// ---- K1b: rinv[c] = rsqrt(sum_b partial[b][c]) ----
__global__ __launch_bounds__(256) void k_rinv(const float* __restrict__ partial,
                                              float* __restrict__ rinv) {
  int c = blockIdx.x * 256 + threadIdx.x;
  float s = 0.f;
  for (int i = 0; i < 128; ++i) s += partial[(size_t)i * V + c];
  rinv[c] = rsqrtf(s);
}

// ---- KT: At[j][v] = adj[v][j] * rinv[v] * rinv[j]  (fp32 in, bf16 out) ----
__global__ __launch_bounds__(256) void k_tn(const float* __restrict__ adj,
                                            const float* __restrict__ rinv,
                                            u16* __restrict__ At) {
  __shared__ float T[64][65];
  int t = threadIdx.x;
  int v0 = blockIdx.x * 64;
  int j0 = blockIdx.y * 64;
  #pragma unroll
  for (int it = 0; it < 2; ++it) {
    int f = t + it * 256;
    int row = f >> 3;          // v offset
    int cc = (f & 7) * 8;      // j chunk
    float rv = rinv[v0 + row];
    const float4* p = (const float4*)(adj + (size_t)(v0 + row) * V + j0 + cc);
    float4 a0 = p[0], a1 = p[1];
    T[row][cc + 0] = a0.x * rv; T[row][cc + 1] = a0.y * rv;
    T[row][cc + 2] = a0.z * rv; T[row][cc + 3] = a0.w * rv;
    T[row][cc + 4] = a1.x * rv; T[row][cc + 5] = a1.y * rv;
    T[row][cc + 6] = a1.z * rv; T[row][cc + 7] = a1.w * rv;
  }
  __syncthreads();
  #pragma unroll
  for (int it = 0; it < 2; ++it) {
    int f = t + it * 256;
    int jr = f >> 3;           // j offset
    int vc = (f & 7) * 8;      // v chunk
    float rj = rinv[j0 + jr];
    u16x8 o;
    #pragma unroll
    for (int k = 0; k < 8; ++k) o[k] = f2b(T[vc + k][jr] * rj);
    *(u16x8*)(At + (size_t)(j0 + jr) * V + v0 + vc) = o;
  }
}

// ---- K2 (MFMA): Yt[(ab*64+e)][v] = sum_d W[d][e] * x[ab,v,d] ----
// A = W^T (M=e, K=d) from LDS; B = x (K=d, N=v) direct from global.
__global__ __launch_bounds__(256) void k_proj(const float* __restrict__ x,
                                              const float* __restrict__ w,
                                              u16* __restrict__ Yt) {
  __shared__ u16 WT[64 * 72];   // WT[e][d] bf16, stride 72 (16B-aligned rows)
  int t = threadIdx.x;
  int ab = blockIdx.x >> 4;
  int v0 = (blockIdx.x & 15) * 128;

  // Build WT: thread t loads w[t*16 .. t*16+15] (d-major), scatters transposed.
  {
    const float4* pw = (const float4*)(w + t * 16);
    float4 c0 = pw[0], c1 = pw[1], c2 = pw[2], c3 = pw[3];
    float vals[16] = {c0.x, c0.y, c0.z, c0.w, c1.x, c1.y, c1.z, c1.w,
                      c2.x, c2.y, c2.z, c2.w, c3.x, c3.y, c3.z, c3.w};
    #pragma unroll
    for (int k = 0; k < 16; ++k) {
      int idx = t * 16 + k;             // idx = d*64 + e
      WT[(idx & 63) * 72 + (idx >> 6)] = f2b(vals[k]);
    }
  }
  __syncthreads();

  int lane = t & 63, wave = t >> 6;
  int q = lane >> 4, r = lane & 15;
  int vbase = v0 + wave * 32;

  bf16x8 a[4][2];   // [m-tile e][k-step]
  #pragma unroll
  for (int i = 0; i < 4; ++i)
    #pragma unroll
    for (int kk = 0; kk < 2; ++kk)
      a[i][kk] = __builtin_bit_cast(bf16x8,
          *(const u16x8*)(WT + (i * 16 + r) * 72 + kk * 32 + q * 8));

  const f32x4 vzero = {0.f, 0.f, 0.f, 0.f};
  f32x4 acc[4][2];
  #pragma unroll
  for (int i = 0; i < 4; ++i) { acc[i][0] = vzero; acc[i][1] = vzero; }

  #pragma unroll
  for (int nt = 0; nt < 2; ++nt) {
    int v = vbase + nt * 16 + r;
    const float* xp = x + ((size_t)ab * V + v) * DD;
    #pragma unroll
    for (int kk = 0; kk < 2; ++kk) {
      const float4* p = (const float4*)(xp + kk * 32 + q * 8);
      float4 b0 = p[0], b1 = p[1];
      u16x8 bu;
      bu[0] = f2b(b0.x); bu[1] = f2b(b0.y); bu[2] = f2b(b0.z); bu[3] = f2b(b0.w);
      bu[4] = f2b(b1.x); bu[5] = f2b(b1.y); bu[6] = f2b(b1.z); bu[7] = f2b(b1.w);
      bf16x8 bf = __builtin_bit_cast(bf16x8, bu);
      #pragma unroll
      for (int i = 0; i < 4; ++i)
        acc[i][nt] = __builtin_amdgcn_mfma_f32_16x16x32_bf16(a[i][kk], bf, acc[i][nt], 0, 0, 0);
    }
  }

  // D layout: col(v) = lane&15, row(e) = quad*4 + reg
  #pragma unroll
  for (int i = 0; i < 4; ++i)
    #pragma unroll
    for (int nt = 0; nt < 2; ++nt) {
      int v = vbase + nt * 16 + r;
      #pragma unroll
      for (int reg = 0; reg < 4; ++reg) {
        int e = i * 16 + q * 4 + reg;
        Yt[(size_t)(ab * 64 + e) * V + v] = f2b(acc[i][nt][reg]);
      }
    }
}

// ---- K3: OUT[j,n] = sum_v At[j,v]*Yt[n,v]; +bias, relu; FP32 out ----
// BK=128 as 4 panels of 32 (panel layout keeps proven 64B-row bank profile).
#define BM 128
#define BN 128
#define PANEL (128 * 32)

__global__ __launch_bounds__(256) void k_gemm(const u16* __restrict__ At,
                                              const u16* __restrict__ Yt,
                                              const float* __restrict__ bias,
                                              float* __restrict__ out) {
  __shared__ u16 Al[4 * PANEL];   // 32 KB
  __shared__ u16 Bl[4 * PANEL];   // 32 KB
  int t = threadIdx.x;
  int m0 = blockIdx.x * BM;
  int n0 = blockIdx.y * BN;
  int lane = t & 63;
  int wave = t >> 6;
  int wm = (wave & 1) * 64;
  int wn = (wave >> 1) * 64;
  int q = lane >> 4;
  int r = lane & 15;

  const f32x4 vzero = {0.f, 0.f, 0.f, 0.f};
  f32x4 acc[4][4];
  #pragma unroll
  for (int i = 0; i < 4; ++i)
    #pragma unroll
    for (int j = 0; j < 4; ++j) acc[i][j] = vzero;

  // gll16 lane map (per panel): eo = (pass*256+t)*8 -> row=eo>>5, col=eo&31.
  int eo0 = t * 8;
  int eo1 = (256 + t) * 8;
  int row0 = eo0 >> 5, col0 = eo0 & 31;
  int row1 = eo1 >> 5, col1 = eo1 & 31;

  for (int k0 = 0; k0 < V; k0 += 128) {
    __syncthreads();
    #pragma unroll
    for (int p = 0; p < 4; ++p) {
      int kp = k0 + p * 32;
      gll16(At + (size_t)(m0 + row0) * V + kp + col0, Al + p * PANEL + eo0);
      gll16(At + (size_t)(m0 + row1) * V + kp + col1, Al + p * PANEL + eo1);
      gll16(Yt + (size_t)(n0 + row0) * V + kp + col0, Bl + p * PANEL + eo0);
      gll16(Yt + (size_t)(n0 + row1) * V + kp + col1, Bl + p * PANEL + eo1);
    }
    __syncthreads();
    #pragma unroll
    for (int p = 0; p < 4; ++p) {
      bf16x8 a[4], b[4];
      #pragma unroll
      for (int i = 0; i < 4; ++i)
        a[i] = __builtin_bit_cast(bf16x8,
            *(const u16x8*)(Al + p * PANEL + (wm + i * 16 + r) * 32 + q * 8));
      #pragma unroll
      for (int j = 0; j < 4; ++j)
        b[j] = __builtin_bit_cast(bf16x8,
            *(const u16x8*)(Bl + p * PANEL + (wn + j * 16 + r) * 32 + q * 8));
      #pragma unroll
      for (int i = 0; i < 4; ++i)
        #pragma unroll
        for (int j = 0; j < 4; ++j)
          acc[i][j] = __builtin_amdgcn_mfma_f32_16x16x32_bf16(a[i], b[j], acc[i][j], 0, 0, 0);
    }
  }

  // epilogue: D layout col(n) = lane&15, row(m) = (lane>>4)*4 + reg
  #pragma unroll
  for (int j = 0; j < 4; ++j) {
    int n = n0 + wn + j * 16 + r;
    int e = n & 63;
    int ab = n >> 6;
    float bv = bias[e];
    float* ob = out + (size_t)ab * (V * DD);
    #pragma unroll
    for (int i = 0; i < 4; ++i) {
      #pragma unroll
      for (int reg = 0; reg < 4; ++reg) {
        int jj = m0 + wm + i * 16 + q * 4 + reg;
        ob[(size_t)jj * DD + e] = fmaxf(acc[i][j][reg] + bv, 0.f);
      }
    }
  }
}

extern "C" void kernel_launch(void* const* d_in, const int* in_sizes, int n_in,
                              void* d_out, int out_size, void* d_ws, size_t ws_size,
                              hipStream_t stream) {
  const float* adj  = (const float*)d_in[0];
  const float* x    = (const float*)d_in[1];
  const float* w    = (const float*)d_in[2];
  const float* bias = (const float*)d_in[3];
  float* out = (float*)d_out;

  // Workspace (24 MB):
  //   At      @ 0    : 2048*2048 bf16 = 8 MB   (live k_tn..k_gemm)
  //   Yt      @ 8 MB : 4096*2048 bf16 = 16 MB  (live k_proj..k_gemm)
  //   partial @ 8 MB : 128*2048 f32 = 1 MB     (overlaps Yt; dead before k_proj)
  //   rinv    @ 9 MB : 2048 f32 = 8 KB         (read by k_tn, dead before k_proj)
  char* ws = (char*)d_ws;
  u16*   At      = (u16*)ws;
  u16*   Yt      = (u16*)(ws + ((size_t)8 << 20));
  float* partial = (float*)(ws + ((size_t)8 << 20));
  float* rinv    = (float*)(ws + ((size_t)9 << 20));

  k_part<<<128, 256, 0, stream>>>(adj, partial);
  k_rinv<<<8, 256, 0, stream>>>(partial, rinv);
  k_tn<<<dim3(32, 32), 256, 0, stream>>>(adj, rinv, At);
  k_proj<<<1024, 256, 0, stream>>>(x, w, Yt);
  k_gemm<<<dim3(16, 32), 256, 0, stream>>>(At, Yt, bias, out);
}

// Round 14
// 149.402 us; speedup vs baseline: 1.2450x; 1.0291x over previous
//
#include <hip/hip_runtime.h>
#include <cstddef>

typedef unsigned short u16;
typedef u16 u16x8 __attribute__((ext_vector_type(8)));
typedef __bf16 bf16x8 __attribute__((ext_vector_type(8)));
typedef float f32x4 __attribute__((ext_vector_type(4)));

static constexpr int V  = 2048;
static constexpr int DD = 64;   // D_IN == D_OUT

__device__ __forceinline__ u16 f2b(float f) {
  union { float f; unsigned int i; } x; x.f = f;
  return (u16)((x.i + 0x7fffu + ((x.i >> 16) & 1u)) >> 16);  // RNE
}

__device__ __forceinline__ void gll16(const void* g, void* l) {
  __builtin_amdgcn_global_load_lds(
      (const __attribute__((address_space(1))) void*)g,
      (__attribute__((address_space(3))) void*)l, 16, 0, 0);
}

// ---- K1: partial column sums of adj: partial[b][c] = sum of 32 rows ----
__global__ __launch_bounds__(256) void k_part(const float* __restrict__ adj,
                                              float* __restrict__ partial) {
  int t = threadIdx.x;
  int r0 = blockIdx.x * 32;
  int c0 = t * 8;
  float acc[8] = {0.f, 0.f, 0.f, 0.f, 0.f, 0.f, 0.f, 0.f};
  for (int r = 0; r < 32; ++r) {
    const float4* p = (const float4*)(adj + (size_t)(r0 + r) * V + c0);
    float4 a0 = p[0], a1 = p[1];
    acc[0] += a0.x; acc[1] += a0.y; acc[2] += a0.z; acc[3] += a0.w;
    acc[4] += a1.x; acc[5] += a1.y; acc[6] += a1.z; acc[7] += a1.w;
  }
  #pragma unroll
  for (int k = 0; k < 8; ++k) partial[(size_t)blockIdx.x * V + c0 + k] = acc[k];
}

// ---- K2 fused: blocks 0..1023 = tn tiles; blocks 1024..2047 = proj tiles ----
__global__ __launch_bounds__(256) void k_prep(const float* __restrict__ adj,
                                              const float* __restrict__ partial,
                                              const float* __restrict__ x,
                                              const float* __restrict__ w,
                                              u16* __restrict__ At,
                                              u16* __restrict__ Yt) {
  __shared__ float T[64][65];          // tn transpose tile (proj aliases as WT)
  __shared__ float rvv[64], rvj[64];   // tn: rinv for v-range / j-range
  int t = threadIdx.x;
  int bid = blockIdx.x;

  if (bid < 1024) {
    // ---------- tn: At[j][v] = adj[v][j] * rinv[v] * rinv[j] ----------
    int v0 = (bid & 31) * 64;
    int j0 = (bid >> 5) * 64;
    // per-block rinv re-reduction from 64 partials (coalesced 64-wide runs)
    if (t < 128) {
      int col = (t < 64) ? (v0 + t) : (j0 + (t - 64));
      float s = 0.f;
      for (int i = 0; i < 64; ++i) s += partial[(size_t)i * V + col];
      float rv = rsqrtf(s);
      if (t < 64) rvv[t] = rv; else rvj[t - 64] = rv;
    }
    __syncthreads();
    #pragma unroll
    for (int it = 0; it < 2; ++it) {
      int f = t + it * 256;
      int row = f >> 3;          // v offset
      int cc = (f & 7) * 8;      // j chunk
      float rv = rvv[row];
      const float4* p = (const float4*)(adj + (size_t)(v0 + row) * V + j0 + cc);
      float4 a0 = p[0], a1 = p[1];
      T[row][cc + 0] = a0.x * rv; T[row][cc + 1] = a0.y * rv;
      T[row][cc + 2] = a0.z * rv; T[row][cc + 3] = a0.w * rv;
      T[row][cc + 4] = a1.x * rv; T[row][cc + 5] = a1.y * rv;
      T[row][cc + 6] = a1.z * rv; T[row][cc + 7] = a1.w * rv;
    }
    __syncthreads();
    #pragma unroll
    for (int it = 0; it < 2; ++it) {
      int f = t + it * 256;
      int jr = f >> 3;           // j offset
      int vc = (f & 7) * 8;      // v chunk
      float rj = rvj[jr];
      u16x8 o;
      #pragma unroll
      for (int k = 0; k < 8; ++k) o[k] = f2b(T[vc + k][jr] * rj);
      *(u16x8*)(At + (size_t)(j0 + jr) * V + v0 + vc) = o;
    }
  } else {
    // ---------- proj (MFMA): Yt[(ab*64+e)][v] = sum_d W[d][e]*x[ab,v,d] ----
    int pb = bid - 1024;
    int ab = pb >> 4;
    int v0 = (pb & 15) * 128;
    u16* WT = (u16*)&T[0][0];   // WT[e][d] bf16, stride 72 (9 KB, fits in T)

    {
      const float4* pw = (const float4*)(w + t * 16);
      float4 c0 = pw[0], c1 = pw[1], c2 = pw[2], c3 = pw[3];
      float vals[16] = {c0.x, c0.y, c0.z, c0.w, c1.x, c1.y, c1.z, c1.w,
                        c2.x, c2.y, c2.z, c2.w, c3.x, c3.y, c3.z, c3.w};
      #pragma unroll
      for (int k = 0; k < 16; ++k) {
        int idx = t * 16 + k;             // idx = d*64 + e
        WT[(idx & 63) * 72 + (idx >> 6)] = f2b(vals[k]);
      }
    }
    __syncthreads();

    int lane = t & 63, wave = t >> 6;
    int q = lane >> 4, r = lane & 15;
    int vbase = v0 + wave * 32;

    bf16x8 a[4][2];   // [m-tile e][k-step]
    #pragma unroll
    for (int i = 0; i < 4; ++i)
      #pragma unroll
      for (int kk = 0; kk < 2; ++kk)
        a[i][kk] = __builtin_bit_cast(bf16x8,
            *(const u16x8*)(WT + (i * 16 + r) * 72 + kk * 32 + q * 8));

    const f32x4 vzero = {0.f, 0.f, 0.f, 0.f};
    f32x4 acc[4][2];
    #pragma unroll
    for (int i = 0; i < 4; ++i) { acc[i][0] = vzero; acc[i][1] = vzero; }

    #pragma unroll
    for (int nt = 0; nt < 2; ++nt) {
      int v = vbase + nt * 16 + r;
      const float* xp = x + ((size_t)ab * V + v) * DD;
      #pragma unroll
      for (int kk = 0; kk < 2; ++kk) {
        const float4* p = (const float4*)(xp + kk * 32 + q * 8);
        float4 b0 = p[0], b1 = p[1];
        u16x8 bu;
        bu[0] = f2b(b0.x); bu[1] = f2b(b0.y); bu[2] = f2b(b0.z); bu[3] = f2b(b0.w);
        bu[4] = f2b(b1.x); bu[5] = f2b(b1.y); bu[6] = f2b(b1.z); bu[7] = f2b(b1.w);
        bf16x8 bf = __builtin_bit_cast(bf16x8, bu);
        #pragma unroll
        for (int i = 0; i < 4; ++i)
          acc[i][nt] = __builtin_amdgcn_mfma_f32_16x16x32_bf16(a[i][kk], bf, acc[i][nt], 0, 0, 0);
      }
    }

    // D layout: col(v) = lane&15, row(e) = quad*4 + reg
    #pragma unroll
    for (int i = 0; i < 4; ++i)
      #pragma unroll
      for (int nt = 0; nt < 2; ++nt) {
        int v = vbase + nt * 16 + r;
        #pragma unroll
        for (int reg = 0; reg < 4; ++reg) {
          int e = i * 16 + q * 4 + reg;
          Yt[(size_t)(ab * 64 + e) * V + v] = f2b(acc[i][nt][reg]);
        }
      }
  }
}

// ---- K3: OUT[j,n] = sum_v At[j,v]*Yt[n,v]; +bias, relu; FP32 out ----
#define BM 128
#define BN 128
#define PANEL (128 * 32)

__global__ __launch_bounds__(256) void k_gemm(const u16* __restrict__ At,
                                              const u16* __restrict__ Yt,
                                              const float* __restrict__ bias,
                                              float* __restrict__ out) {
  __shared__ u16 Al[4 * PANEL];   // 32 KB
  __shared__ u16 Bl[4 * PANEL];   // 32 KB
  int t = threadIdx.x;
  int m0 = blockIdx.x * BM;
  int n0 = blockIdx.y * BN;
  int lane = t & 63;
  int wave = t >> 6;
  int wm = (wave & 1) * 64;
  int wn = (wave >> 1) * 64;
  int q = lane >> 4;
  int r = lane & 15;

  const f32x4 vzero = {0.f, 0.f, 0.f, 0.f};
  f32x4 acc[4][4];
  #pragma unroll
  for (int i = 0; i < 4; ++i)
    #pragma unroll
    for (int j = 0; j < 4; ++j) acc[i][j] = vzero;

  int eo0 = t * 8;
  int eo1 = (256 + t) * 8;
  int row0 = eo0 >> 5, col0 = eo0 & 31;
  int row1 = eo1 >> 5, col1 = eo1 & 31;

  for (int k0 = 0; k0 < V; k0 += 128) {
    __syncthreads();
    #pragma unroll
    for (int p = 0; p < 4; ++p) {
      int kp = k0 + p * 32;
      gll16(At + (size_t)(m0 + row0) * V + kp + col0, Al + p * PANEL + eo0);
      gll16(At + (size_t)(m0 + row1) * V + kp + col1, Al + p * PANEL + eo1);
      gll16(Yt + (size_t)(n0 + row0) * V + kp + col0, Bl + p * PANEL + eo0);
      gll16(Yt + (size_t)(n0 + row1) * V + kp + col1, Bl + p * PANEL + eo1);
    }
    __syncthreads();
    #pragma unroll
    for (int p = 0; p < 4; ++p) {
      bf16x8 a[4], b[4];
      #pragma unroll
      for (int i = 0; i < 4; ++i)
        a[i] = __builtin_bit_cast(bf16x8,
            *(const u16x8*)(Al + p * PANEL + (wm + i * 16 + r) * 32 + q * 8));
      #pragma unroll
      for (int j = 0; j < 4; ++j)
        b[j] = __builtin_bit_cast(bf16x8,
            *(const u16x8*)(Bl + p * PANEL + (wn + j * 16 + r) * 32 + q * 8));
      #pragma unroll
      for (int i = 0; i < 4; ++i)
        #pragma unroll
        for (int j = 0; j < 4; ++j)
          acc[i][j] = __builtin_amdgcn_mfma_f32_16x16x32_bf16(a[i], b[j], acc[i][j], 0, 0, 0);
    }
  }

  #pragma unroll
  for (int j = 0; j < 4; ++j) {
    int n = n0 + wn + j * 16 + r;
    int e = n & 63;
    int ab = n >> 6;
    float bv = bias[e];
    float* ob = out + (size_t)ab * (V * DD);
    #pragma unroll
    for (int i = 0; i < 4; ++i) {
      #pragma unroll
      for (int reg = 0; reg < 4; ++reg) {
        int jj = m0 + wm + i * 16 + q * 4 + reg;
        ob[(size_t)jj * DD + e] = fmaxf(acc[i][j][reg] + bv, 0.f);
      }
    }
  }
}

extern "C" void kernel_launch(void* const* d_in, const int* in_sizes, int n_in,
                              void* d_out, int out_size, void* d_ws, size_t ws_size,
                              hipStream_t stream) {
  const float* adj  = (const float*)d_in[0];
  const float* x    = (const float*)d_in[1];
  const float* w    = (const float*)d_in[2];
  const float* bias = (const float*)d_in[3];
  float* out = (float*)d_out;

  // Workspace (24.5 MB; >=25 MB proven available in round 11):
  //   At      @ 0     : 2048*2048 bf16 = 8 MB   (live k_prep..k_gemm)
  //   Yt      @ 8 MB  : 4096*2048 bf16 = 16 MB  (live k_prep..k_gemm)
  //   partial @ 24 MB : 64*2048 f32 = 512 KB    (live k_part..k_prep; must NOT
  //                                              overlap Yt — read while Yt written)
  char* ws = (char*)d_ws;
  u16*   At      = (u16*)ws;
  u16*   Yt      = (u16*)(ws + ((size_t)8 << 20));
  float* partial = (float*)(ws + ((size_t)24 << 20));

  k_part<<<64, 256, 0, stream>>>(adj, partial);
  k_prep<<<2048, 256, 0, stream>>>(adj, partial, x, w, At, Yt);
  k_gemm<<<dim3(16, 32), 256, 0, stream>>>(At, Yt, bias, out);
}